// Round 1
// baseline (161.692 us; speedup 1.0000x reference)
//
#include <hip/hip_runtime.h>
#include <math.h>

#define N_     256
#define C_     2048
#define HW_    49
#define CHUNKS 8
#define CPB    (C_/CHUNKS)   // 256 channels per block
#define TILE_C 64
#define NG     5             // groups: sum, u0, u1, t0, t1

// ---------------------------------------------------------------------------
// Kernel 1: 5 weighted channel-reductions over x, chunked over channels.
// part[n][chunk][g*49+p] = sum over this chunk's channels of x[n,c,p]*w_g[c]
//   w_0 = 1, w_1 = W[0,c], w_2 = W[1,c], w_3 = W[0,C+c], w_4 = W[1,C+c]
// ---------------------------------------------------------------------------
__global__ __launch_bounds__(256) void k_reduce(const float* __restrict__ x,
                                                const float* __restrict__ Wm,
                                                float* __restrict__ part) {
  const int chunk = blockIdx.x;   // 0..7
  const int n     = blockIdx.y;   // 0..255
  const int t     = threadIdx.x;

  __shared__ float4 tile4[(TILE_C*HW_)/4];   // 3136 floats, 16B-aligned
  __shared__ float  wt[NG][TILE_C];
  float* tile = (float*)tile4;

  const int g = t / HW_;          // 0..5 (g==5 -> idle in reduce phase)
  const int p = t - g*HW_;

  float acc = 0.f;

  for (int tc = 0; tc < CPB; tc += TILE_C) {
    const int c0 = chunk*CPB + tc;
    // stage x tile: 64 channels x 49 pos, contiguous, float4-aligned
    // (element offset 49*(2048n + c0) with c0 % 64 == 0 is divisible by 4)
    const float4* src = (const float4*)(x + ((size_t)n*C_ + (size_t)c0)*HW_);
    #pragma unroll
    for (int i = 0; i < 4; ++i) {
      int idx = t + i*256;
      if (idx < (TILE_C*HW_)/4) tile4[idx] = src[idx];
    }
    // stage weights for this channel tile
    for (int i = t; i < NG*TILE_C; i += 256) {
      int gg = i / TILE_C, cc = i - gg*TILE_C;
      float w;
      if (gg == 0) w = 1.f;
      else {
        int row  = (gg-1) & 1;   // which W row (output o)
        int half = (gg-1) >> 1;  // 0: first C cols (u), 1: second C cols (t)
        w = Wm[row*(2*C_) + half*C_ + c0 + cc];
      }
      wt[gg][cc] = w;
    }
    __syncthreads();
    if (g < NG) {
      #pragma unroll 8
      for (int c = 0; c < TILE_C; ++c)
        acc = fmaf(tile[c*HW_ + p], wt[g][c], acc);
    }
    __syncthreads();
  }
  if (g < NG)
    part[((size_t)n*CHUNKS + chunk)*(NG*HW_) + t] = acc;
}

// ---------------------------------------------------------------------------
// Kernel 2: per-n epilogue. One block per n.
// ---------------------------------------------------------------------------
__global__ __launch_bounds__(256) void k_final(const float* __restrict__ part,
                                               const float* __restrict__ mask,
                                               const float* __restrict__ b,
                                               float* __restrict__ out) {
  const int n = blockIdx.x;
  const int t = threadIdx.x;
  __shared__ float red[NG*HW_];

  if (t < NG*HW_) {
    float a = 0.f;
    #pragma unroll
    for (int ch = 0; ch < CHUNKS; ++ch)
      a += part[((size_t)n*CHUNKS + ch)*(NG*HW_) + t];
    red[t] = a;
  }
  __syncthreads();

  if (t < 64) {
    const int  p   = t;
    const bool act = (p < HW_);

    // threshold = mean(mask[n]); binary mask strict >
    float m = act ? mask[n*HW_ + p] : 0.f;
    float tot = m;
    #pragma unroll
    for (int off = 32; off; off >>= 1) tot += __shfl_xor(tot, off);
    const float thr = tot / 49.f;

    // masked_mean and first-index argmax over 49 positions
    float s  = act ? red[0*HW_ + p] : 0.f;
    float mm = act ? ((m > thr) ? (s * (1.f/2048.f)) : 0.f) : -INFINITY;
    float best = mm;
    int   bidx = act ? p : 64;
    #pragma unroll
    for (int off = 32; off; off >>= 1) {
      float ov = __shfl_xor(best, off);
      int   oi = __shfl_xor(bidx, off);
      if (ov > best || (ov == best && oi < bidx)) { best = ov; bidx = oi; }
    }
    const int mi = bidx;   // uniform across wave

    const float u0mi = red[1*HW_ + mi];
    const float u1mi = red[2*HW_ + mi];

    float pred0 = 0.f, pred1 = 0.f;
    if (act) {
      pred0 = fmaxf(u0mi + red[3*HW_ + p] + b[0], 0.f);
      pred1 = fmaxf(u1mi + red[4*HW_ + p] + b[1], 0.f);
      if (p == mi) { pred0 = 0.f; pred1 = 0.f; }
    }

    // geometry
    const int ii = p / 7,  jj = p - ii*7;
    const int ai = mi / 7, aj = mi - ai*7;
    const float ri = (float)(ii - ai) / 7.f;
    const float rj = (float)(jj - aj) / 7.f;
    const float dist = sqrtf(ri*ri + rj*rj);
    const float ang  = (atan2f(rj, ri) / 3.14159274101257324f + 1.f) * 0.5f;

    float gap = pred1 - ang;
    if (gap < 0.f) gap += 1.f;
    float gsum = act ? gap : 0.f;
    #pragma unroll
    for (int off = 32; off; off >>= 1) gsum += __shfl_xor(gsum, off);
    const float gmean = gsum / 49.f;

    if (act) {
      const float dl = pred0 - dist;
      const float ga = gap - gmean;
      out[n*HW_ + p] = dl*dl + ga*ga;
    }
  }
}

extern "C" void kernel_launch(void* const* d_in, const int* in_sizes, int n_in,
                              void* d_out, int out_size, void* d_ws, size_t ws_size,
                              hipStream_t stream) {
  const float* x    = (const float*)d_in[0];  // (256, 2048, 7, 7)
  const float* mask = (const float*)d_in[1];  // (256, 7, 7)
  const float* Wm   = (const float*)d_in[2];  // (2, 4096)
  const float* b    = (const float*)d_in[3];  // (2,)
  float* out  = (float*)d_out;                // (256, 7, 7)
  float* part = (float*)d_ws;                 // 256*8*245 floats = 1.92 MB

  dim3 g1(CHUNKS, N_);
  k_reduce<<<g1, 256, 0, stream>>>(x, Wm, part);
  k_final<<<N_, 256, 0, stream>>>(part, mask, b, out);
}